// Round 4
// baseline (416.515 us; speedup 1.0000x reference)
//
#include <hip/hip_runtime.h>

#define TOK 8192   // B*S
#define DIM 512    // D
#define NE  32     // experts
#define KTOT (NE * DIM)

#define BM 128
#define BN 128
#define BK 64

typedef float f32x4 __attribute__((ext_vector_type(4)));
typedef short s16x8 __attribute__((ext_vector_type(8)));

// LDS-only barrier: drains ds ops (lgkmcnt) but leaves global prefetch loads
// (vmcnt) in flight across the barrier — the whole point of the restructure.
#define BAR_LDS() asm volatile("s_waitcnt lgkmcnt(0)\n\ts_barrier" ::: "memory")

__device__ __forceinline__ ushort f2bf(float f) {
    unsigned u = __builtin_bit_cast(unsigned, f);
    unsigned r = (u + 0x7fffu + ((u >> 16) & 1u)) >> 16;
    return (ushort)r;
}

// ---- expert_w [E][D][F] fp32 -> Wt [F][E*D] bf16 (tiled transpose) ----
__global__ __launch_bounds__(256) void k_cvt_wt(const float* __restrict__ w,
                                                ushort* __restrict__ wt) {
    __shared__ float tile[32][33];
    const int e = blockIdx.z;
    const int f0 = blockIdx.x * 32;
    const int d0 = blockIdx.y * 32;
    const int tx = threadIdx.x, ty = threadIdx.y;
    const float* we = w + (size_t)e * DIM * DIM;
#pragma unroll
    for (int i = ty; i < 32; i += 8)
        tile[i][tx] = we[(size_t)(d0 + i) * DIM + f0 + tx];
    __syncthreads();
#pragma unroll
    for (int i = ty; i < 32; i += 8)
        wt[(size_t)(f0 + i) * KTOT + e * DIM + d0 + tx] = f2bf(tile[tx][i]);
}

// -------- gate softmax (fp32 exact) + x fp32->bf16 conversion (fused) -----
__global__ __launch_bounds__(256) void k_gates(const float* __restrict__ x,
                                               const float* __restrict__ gw,
                                               const float* __restrict__ gb,
                                               float* __restrict__ G,
                                               ushort* __restrict__ xb) {
    __shared__ float xs[DIM];
    __shared__ float part[256];
    __shared__ float logits[NE];
    const int t = blockIdx.x;
    const int tid = threadIdx.x;
    float v0 = x[(size_t)t * DIM + tid];
    float v1 = x[(size_t)t * DIM + tid + 256];
    xs[tid] = v0;
    xs[tid + 256] = v1;
    xb[(size_t)t * DIM + tid] = f2bf(v0);
    xb[(size_t)t * DIM + tid + 256] = f2bf(v1);
    __syncthreads();
    const int e = tid & 31;
    const int ch = tid >> 5;   // 0..7
    float s = 0.f;
#pragma unroll 8
    for (int i = 0; i < 64; ++i) {
        int d = ch * 64 + i;
        s += xs[d] * gw[d * NE + e];
    }
    part[tid] = s;
    __syncthreads();
    if (tid < NE) {
        float l = gb[tid];
#pragma unroll
        for (int c = 0; c < 8; ++c) l += part[c * 32 + tid];
        logits[tid] = l;
    }
    __syncthreads();
    float ex = 0.f;
    if (tid < NE) {
        float mx = -1e30f;
#pragma unroll
        for (int o = 0; o < NE; ++o) mx = fmaxf(mx, logits[o]);
        ex = expf(logits[tid] - mx);
        part[tid] = ex;
    }
    __syncthreads();
    if (tid < NE) {
        float sum = 0.f;
#pragma unroll
        for (int o = 0; o < NE; ++o) sum += part[o];
        G[(size_t)t * NE + tid] = ex / sum;
    }
}

// ---------------- main MFMA GEMM, register-prefetch pipelined ----------------
// One block = one 128x128 tile; 4 waves of 64x64 (2m x 2n). Single LDS A/B
// chunk buffers (BK=64); next chunk prefetched to VGPRs while computing the
// current one; barriers drain LDS only (global loads stay in flight).
// LDS tiles XOR-swizzled on the write side: LDS[row][c ^ (row&7)] = G[row][c].
__global__ __launch_bounds__(256, 1) void k_moe_gemm(const ushort* __restrict__ xb,
                                                     const ushort* __restrict__ wt,
                                                     const float* __restrict__ G,
                                                     float* __restrict__ out) {
    __shared__ __align__(16) ushort As[BM * BK];   // 16 KB
    __shared__ __align__(16) ushort Bs[BN * BK];   // 16 KB
    __shared__ float Gs[NE][BM];                   // 16 KB

    const int tid = threadIdx.x;
    const int m0 = blockIdx.y * BM;
    const int n0 = blockIdx.x * BN;

    for (int i = tid; i < NE * BM; i += 256) {
        int e = i >> 7, r = i & 127;
        Gs[e][r] = G[(size_t)(m0 + r) * NE + e];
    }

    const int lane = tid & 63;
    const int wave = tid >> 6;           // 0..3
    const int wm = (wave & 1) * 64;
    const int wn = (wave >> 1) * 64;
    const int l15 = lane & 15;
    const int q = lane >> 4;             // 0..3

    // ---- staging geometry: 256 thr x 64 B = one 16 KB chunk per tile ----
    const int srow = tid >> 1;           // 0..127
    const int shalf = tid & 1;           // which 32-elem half of the 64-elem row
    const ushort* aP = xb + (size_t)(m0 + srow) * DIM + shalf * 32;
    const ushort* bP = wt + (size_t)(n0 + srow) * KTOT + shalf * 32;
    int wr[4];
#pragma unroll
    for (int i = 0; i < 4; ++i) {
        int c = shalf * 4 + i;
        wr[i] = srow * 128 + ((c ^ (srow & 7)) << 4);
    }

    // ---- reader addresses (precomputed byte offsets) ----
    int ra[4][2], rb[4][2];
#pragma unroll
    for (int i = 0; i < 4; ++i) {
        int rowA = wm + i * 16 + l15;
        int rowB = wn + i * 16 + l15;
#pragma unroll
        for (int ks = 0; ks < 2; ++ks) {
            int c = ks * 4 + q;
            ra[i][ks] = rowA * 128 + ((c ^ (rowA & 7)) << 4);
            rb[i][ks] = rowB * 128 + ((c ^ (rowB & 7)) << 4);
        }
    }

    const f32x4 zv = {0.f, 0.f, 0.f, 0.f};
    f32x4 acc[4][4], pacc[4][4];
#pragma unroll
    for (int i = 0; i < 4; ++i)
#pragma unroll
        for (int j = 0; j < 4; ++j) { acc[i][j] = zv; pacc[i][j] = zv; }

    // ---- prologue: stage chunk 0 (A kt=0, B id=0) ----
    {
        const uint4* ap = (const uint4*)aP;
        const uint4* bp = (const uint4*)bP;
        uint4 av[4], bv[4];
#pragma unroll
        for (int k = 0; k < 4; ++k) { av[k] = ap[k]; bv[k] = bp[k]; }
#pragma unroll
        for (int k = 0; k < 4; ++k) {
            *(uint4*)((char*)As + wr[k]) = av[k];
            *(uint4*)((char*)Bs + wr[k]) = bv[k];
        }
        BAR_LDS();
    }

#pragma unroll 1
    for (int id = 0; id < 256; ++id) {
        const int kt = id & 7;
        const int nid = (id + 1) & 255;   // wraps to chunk 0 at the end (harmless)

        // prefetch next chunks into registers (stay in flight across compute)
        uint4 av[4], bv[4];
        {
            const uint4* ap = (const uint4*)(aP + (size_t)(nid & 7) * 64);
            const uint4* bp = (const uint4*)(bP + (size_t)nid * 64);
#pragma unroll
            for (int k = 0; k < 4; ++k) { av[k] = ap[k]; bv[k] = bp[k]; }
        }
        __builtin_amdgcn_sched_barrier(0);   // keep prefetch issue above compute

        // compute current chunk from LDS
#pragma unroll
        for (int ks = 0; ks < 2; ++ks) {
            s16x8 a[4], b[4];
#pragma unroll
            for (int i = 0; i < 4; ++i)
                a[i] = *(const s16x8*)((const char*)As + ra[i][ks]);
#pragma unroll
            for (int j = 0; j < 4; ++j)
                b[j] = *(const s16x8*)((const char*)Bs + rb[j][ks]);
#pragma unroll
            for (int i = 0; i < 4; ++i)
#pragma unroll
                for (int j = 0; j < 4; ++j)
                    pacc[i][j] = __builtin_amdgcn_mfma_f32_16x16x32_bf16(
                        a[i], b[j], pacc[i][j], 0, 0, 0);
        }

        BAR_LDS();   // all reads of current chunk done
#pragma unroll
        for (int k = 0; k < 4; ++k) {
            *(uint4*)((char*)As + wr[k]) = av[k];   // vmcnt wait inserted here
            *(uint4*)((char*)Bs + wr[k]) = bv[k];
        }
        BAR_LDS();   // next chunk visible

        if (kt == 7) {
            const int e = id >> 3;
#pragma unroll
            for (int i = 0; i < 4; ++i) {
                const int tl = wm + i * 16 + q * 4;
                const float g0 = Gs[e][tl + 0];
                const float g1 = Gs[e][tl + 1];
                const float g2 = Gs[e][tl + 2];
                const float g3 = Gs[e][tl + 3];
#pragma unroll
                for (int j = 0; j < 4; ++j) {
                    acc[i][j][0] += g0 * pacc[i][j][0];
                    acc[i][j][1] += g1 * pacc[i][j][1];
                    acc[i][j][2] += g2 * pacc[i][j][2];
                    acc[i][j][3] += g3 * pacc[i][j][3];
                    pacc[i][j] = zv;
                }
            }
        }
    }

    // epilogue: plain stores (each output element owned by exactly one lane)
#pragma unroll
    for (int i = 0; i < 4; ++i) {
        const int tl = m0 + wm + i * 16 + q * 4;
#pragma unroll
        for (int j = 0; j < 4; ++j) {
            const int f = n0 + wn + j * 16 + l15;
            float* p = out + (size_t)tl * DIM + f;
            p[0 * DIM] = acc[i][j][0];
            p[1 * DIM] = acc[i][j][1];
            p[2 * DIM] = acc[i][j][2];
            p[3 * DIM] = acc[i][j][3];
        }
    }
}

extern "C" void kernel_launch(void* const* d_in, const int* in_sizes, int n_in,
                              void* d_out, int out_size, void* d_ws, size_t ws_size,
                              hipStream_t stream) {
    const float* x  = (const float*)d_in[0];   // [8192][512]
    const float* gw = (const float*)d_in[1];   // [512][32]
    const float* gb = (const float*)d_in[2];   // [32]
    const float* w  = (const float*)d_in[3];   // [32][512][512]
    float* out = (float*)d_out;                // [8192][512] fp32

    char* ws = (char*)d_ws;
    ushort* xb = (ushort*)ws;                            // 8 MiB
    ushort* wt = (ushort*)(ws + (8u << 20));             // 16 MiB
    float*  G  = (float*)(ws + (24u << 20));             // 1 MiB

    k_cvt_wt<<<dim3(16, 16, NE), dim3(32, 8, 1), 0, stream>>>(w, wt);
    k_gates<<<dim3(TOK), dim3(256), 0, stream>>>(x, gw, gb, G, xb);
    k_moe_gemm<<<dim3(DIM / BN, TOK / BM), dim3(256), 0, stream>>>(xb, wt, G, out);
}

// Round 5
// 257.753 us; speedup vs baseline: 1.6159x; 1.6159x over previous
//
#include <hip/hip_runtime.h>

#define TOK 8192   // B*S
#define DIM 512    // D
#define NE  32     // experts
#define KTOT (NE * DIM)

#define BM 128
#define BN 128
#define BK 64

typedef float f32x4 __attribute__((ext_vector_type(4)));
typedef short s16x8 __attribute__((ext_vector_type(8)));

typedef const void __attribute__((address_space(1)))* gp1_t;
typedef void __attribute__((address_space(3)))* lp3_t;

__device__ __forceinline__ void gl_lds16(const void* g, void* l) {
    __builtin_amdgcn_global_load_lds((gp1_t)g, (lp3_t)l, 16, 0, 0);
}

__device__ __forceinline__ ushort f2bf(float f) {
    unsigned u = __builtin_bit_cast(unsigned, f);
    unsigned r = (u + 0x7fffu + ((u >> 16) & 1u)) >> 16;
    return (ushort)r;
}

// ---- expert_w [E][D][F] fp32 -> Wt [F][E*D] bf16 (tiled transpose) ----
__global__ __launch_bounds__(256) void k_cvt_wt(const float* __restrict__ w,
                                                ushort* __restrict__ wt) {
    __shared__ float tile[32][33];
    const int e = blockIdx.z;
    const int f0 = blockIdx.x * 32;
    const int d0 = blockIdx.y * 32;
    const int tx = threadIdx.x, ty = threadIdx.y;
    const float* we = w + (size_t)e * DIM * DIM;
#pragma unroll
    for (int i = ty; i < 32; i += 8)
        tile[i][tx] = we[(size_t)(d0 + i) * DIM + f0 + tx];
    __syncthreads();
#pragma unroll
    for (int i = ty; i < 32; i += 8)
        wt[(size_t)(f0 + i) * KTOT + e * DIM + d0 + tx] = f2bf(tile[tx][i]);
}

// -------- gate softmax (fp32 exact) + x fp32->bf16 conversion (fused) -----
__global__ __launch_bounds__(256) void k_gates(const float* __restrict__ x,
                                               const float* __restrict__ gw,
                                               const float* __restrict__ gb,
                                               float* __restrict__ G,
                                               ushort* __restrict__ xb) {
    __shared__ float xs[DIM];
    __shared__ float part[256];
    __shared__ float logits[NE];
    const int t = blockIdx.x;
    const int tid = threadIdx.x;
    float v0 = x[(size_t)t * DIM + tid];
    float v1 = x[(size_t)t * DIM + tid + 256];
    xs[tid] = v0;
    xs[tid + 256] = v1;
    xb[(size_t)t * DIM + tid] = f2bf(v0);
    xb[(size_t)t * DIM + tid + 256] = f2bf(v1);
    __syncthreads();
    const int e = tid & 31;
    const int ch = tid >> 5;   // 0..7
    float s = 0.f;
#pragma unroll 8
    for (int i = 0; i < 64; ++i) {
        int d = ch * 64 + i;
        s += xs[d] * gw[d * NE + e];
    }
    part[tid] = s;
    __syncthreads();
    if (tid < NE) {
        float l = gb[tid];
#pragma unroll
        for (int c = 0; c < 8; ++c) l += part[c * 32 + tid];
        logits[tid] = l;
    }
    __syncthreads();
    float ex = 0.f;
    if (tid < NE) {
        float mx = -1e30f;
#pragma unroll
        for (int o = 0; o < NE; ++o) mx = fmaxf(mx, logits[o]);
        ex = expf(logits[tid] - mx);
        part[tid] = ex;
    }
    __syncthreads();
    if (tid < NE) {
        float sum = 0.f;
#pragma unroll
        for (int o = 0; o < NE; ++o) sum += part[o];
        G[(size_t)t * NE + tid] = ex / sum;
    }
}

// ---------------- main MFMA GEMM with per-expert gate fold ----------------
// R3 body + expert z-split for occupancy: blockIdx.z selects a 16-expert
// half; z=0 writes `out`, z=1 writes partial `P` (deterministic two-phase
// sum — no atomics, no memset). 512 thr = 8 waves (4m x 2n), wave = 32x64.
// LDS XOR-swizzle: LDS[row][c] = Global[row][c ^ (row&7)], c = 16B chunk
// (applied on the GLOBAL address at staging; readers un-swizzle).
__global__ __launch_bounds__(512, 2) void k_moe_gemm(const ushort* __restrict__ xb,
                                                     const ushort* __restrict__ wt,
                                                     const float* __restrict__ G,
                                                     float* __restrict__ out0,
                                                     float* __restrict__ out1) {
    __shared__ __align__(16) ushort As[BM * BK];   // 16 KB
    __shared__ __align__(16) ushort Bs[BN * BK];   // 16 KB
    __shared__ float Gs[BM][17];                   // 8.7 KB (this half's gates)

    const int tid = threadIdx.x;
    const int m0 = blockIdx.y * BM;
    const int n0 = blockIdx.x * BN;
    const int e0 = blockIdx.z * 16;
    float* __restrict__ dst = blockIdx.z ? out1 : out0;

    for (int i = tid; i < BM * 16; i += 512) {
        int r = i >> 4, c = i & 15;
        Gs[r][c] = G[(size_t)(m0 + r) * NE + e0 + c];
    }

    const int lane = tid & 63;
    const int wave = tid >> 6;            // 0..7
    const int wm = (wave & 3) * 32;       // 4 m-positions
    const int wn = (wave >> 2) * 64;      // 2 n-positions
    const int l15 = lane & 15;
    const int q = lane >> 4;              // 0..3
    const int keyR = l15 & 7;             // reader swizzle key (row & 7)

    const f32x4 zv = {0.f, 0.f, 0.f, 0.f};
    f32x4 acc[2][4];
#pragma unroll
    for (int i = 0; i < 2; ++i)
#pragma unroll
        for (int j = 0; j < 4; ++j) acc[i][j] = zv;

    // staging map: 512 thr * 16B = 8KB/round; tiles are 16KB -> 2 rounds
    const int srow = tid >> 3;                       // 0..63 (row&7 == srow&7)
    const int chunk = tid & 7;                       // 16B chunk in 128B row
    const int scol = ((chunk ^ (srow & 7)) * 8);     // swizzled global column
    const ushort* aBase = xb + (size_t)(m0 + srow) * DIM + scol;
    const ushort* bBase = wt + (size_t)(n0 + srow) * KTOT + scol;
    char* aLds = (char*)As + tid * 16;
    char* bLds = (char*)Bs + tid * 16;

#pragma unroll 1
    for (int ee = 0; ee < 16; ++ee) {
        const int e = e0 + ee;
        f32x4 pacc[2][4];
#pragma unroll
        for (int i = 0; i < 2; ++i)
#pragma unroll
            for (int j = 0; j < 4; ++j) pacc[i][j] = zv;

#pragma unroll 1
        for (int kt = 0; kt < 8; ++kt) {
            const int kd = kt * BK;
            const ushort* aS = aBase + kd;
            const ushort* bS = bBase + (size_t)e * DIM + kd;
            gl_lds16(aS, aLds);
            gl_lds16(aS + (size_t)64 * DIM, aLds + 8192);
            gl_lds16(bS, bLds);
            gl_lds16(bS + (size_t)64 * KTOT, bLds + 8192);
            __syncthreads();
#pragma unroll
            for (int ks = 0; ks < 2; ++ks) {
                const int swz = ((ks * 4 + q) ^ keyR) * 16;  // un-swizzle
                s16x8 a[2], b[4];
#pragma unroll
                for (int i = 0; i < 2; ++i)
                    a[i] = *(const s16x8*)((const char*)As +
                           (wm + i * 16 + l15) * (BK * 2) + swz);
#pragma unroll
                for (int j = 0; j < 4; ++j)
                    b[j] = *(const s16x8*)((const char*)Bs +
                           (wn + j * 16 + l15) * (BK * 2) + swz);
#pragma unroll
                for (int i = 0; i < 2; ++i)
#pragma unroll
                    for (int j = 0; j < 4; ++j)
                        pacc[i][j] = __builtin_amdgcn_mfma_f32_16x16x32_bf16(
                            a[i], b[j], pacc[i][j], 0, 0, 0);
            }
            __syncthreads();
        }

        // fold expert segment into master with per-token gate
#pragma unroll
        for (int i = 0; i < 2; ++i) {
            const int tl = wm + i * 16 + q * 4;
            const float g0 = Gs[tl + 0][ee];
            const float g1 = Gs[tl + 1][ee];
            const float g2 = Gs[tl + 2][ee];
            const float g3 = Gs[tl + 3][ee];
#pragma unroll
            for (int j = 0; j < 4; ++j) {
                acc[i][j][0] += g0 * pacc[i][j][0];
                acc[i][j][1] += g1 * pacc[i][j][1];
                acc[i][j][2] += g2 * pacc[i][j][2];
                acc[i][j][3] += g3 * pacc[i][j][3];
            }
        }
    }

    // epilogue: plain stores (each element of dst owned by exactly one lane)
#pragma unroll
    for (int i = 0; i < 2; ++i) {
        const int tl = m0 + wm + i * 16 + q * 4;
#pragma unroll
        for (int j = 0; j < 4; ++j) {
            const int f = n0 + wn + j * 16 + l15;
            float* p = dst + (size_t)tl * DIM + f;
            p[0 * DIM] = acc[i][j][0];
            p[1 * DIM] = acc[i][j][1];
            p[2 * DIM] = acc[i][j][2];
            p[3 * DIM] = acc[i][j][3];
        }
    }
}

// ---- deterministic two-phase sum: out += P (both fully written upstream) ----
__global__ __launch_bounds__(256) void k_reduce(float* __restrict__ out,
                                                const float* __restrict__ P) {
    int i = (blockIdx.x * 256 + threadIdx.x) * 4;
    float4 a = *(const float4*)(out + i);
    float4 b = *(const float4*)(P + i);
    a.x += b.x; a.y += b.y; a.z += b.z; a.w += b.w;
    *(float4*)(out + i) = a;
}

extern "C" void kernel_launch(void* const* d_in, const int* in_sizes, int n_in,
                              void* d_out, int out_size, void* d_ws, size_t ws_size,
                              hipStream_t stream) {
    const float* x  = (const float*)d_in[0];   // [8192][512]
    const float* gw = (const float*)d_in[1];   // [512][32]
    const float* gb = (const float*)d_in[2];   // [32]
    const float* w  = (const float*)d_in[3];   // [32][512][512]
    float* out = (float*)d_out;                // [8192][512] fp32

    char* ws = (char*)d_ws;
    ushort* xb = (ushort*)ws;                            // 8 MiB
    ushort* wt = (ushort*)(ws + (8u << 20));             // 16 MiB
    float*  G  = (float*)(ws + (24u << 20));             // 1 MiB
    float*  P  = (float*)(ws + (25u << 20));             // 16 MiB partial

    k_cvt_wt<<<dim3(16, 16, NE), dim3(32, 8, 1), 0, stream>>>(w, wt);
    k_gates<<<dim3(TOK), dim3(256), 0, stream>>>(x, gw, gb, G, xb);
    k_moe_gemm<<<dim3(DIM / BN, TOK / BM, 2), dim3(512), 0, stream>>>(xb, wt, G, out, P);
    k_reduce<<<dim3(TOK * DIM / (256 * 4)), dim3(256), 0, stream>>>(out, P);
}